// Round 1
// baseline (106.965 us; speedup 1.0000x reference)
//
#include <hip/hip_runtime.h>
#include <math.h>

#define DIM 4096     // D, power of 2: 12 FWHT stages
#define ROWS 2048    // B

// ---- pre-kernel: g = g_mu + softplus(g_rho) * epsilon  (4096 floats into ws)
__global__ void g_precompute(const float* __restrict__ eps,
                             const float* __restrict__ g_mu,
                             const float* __restrict__ g_rho,
                             float* __restrict__ g, int n) {
    int i = blockIdx.x * blockDim.x + threadIdx.x;
    if (i < n) {
        float sp = log1pf(expf(g_rho[i]));   // g_rho in [-5,-4], no overflow risk
        g[i] = g_mu[i] + sp * eps[i];
    }
}

__device__ __forceinline__ float4 f4mul(float4 a, float4 b) {
    return make_float4(a.x * b.x, a.y * b.y, a.z * b.z, a.w * b.w);
}

// One cross-lane butterfly stage (bit position = log2(m)+2), sign via fma:
// lower lane (bit clear): v + p ; upper lane (bit set): p - v  == fma(sg, v, p)
__device__ __forceinline__ void lane_stage(float4 v[16], int m, float sg) {
#pragma unroll
    for (int j = 0; j < 16; ++j) {
        float px = __shfl_xor(v[j].x, m, 64);
        float py = __shfl_xor(v[j].y, m, 64);
        float pz = __shfl_xor(v[j].z, m, 64);
        float pw = __shfl_xor(v[j].w, m, 64);
        v[j].x = fmaf(sg, v[j].x, px);
        v[j].y = fmaf(sg, v[j].y, py);
        v[j].z = fmaf(sg, v[j].z, pz);
        v[j].w = fmaf(sg, v[j].w, pw);
    }
}

// Full 4096-pt unnormalized FWHT over v[16] (element e = 4*lane + 256*j + i).
// Stage order across bit positions is free (tensor-product factors commute).
__device__ __forceinline__ void fwht4096(float4 v[16], const float sg[6]) {
    // bits 0,1: within each float4
#pragma unroll
    for (int j = 0; j < 16; ++j) {
        float4 a = v[j];
        float t0 = a.x + a.y, t1 = a.x - a.y;
        float t2 = a.z + a.w, t3 = a.z - a.w;
        v[j] = make_float4(t0 + t2, t1 + t3, t0 - t2, t1 - t3);
    }
    // bits 2..7: across lanes (xor masks 1..32, all intra-wave on wave64)
#pragma unroll
    for (int s = 0; s < 6; ++s)
        lane_stage(v, 1 << s, sg[s]);
    // bits 8..11: across the j index, in registers
#pragma unroll
    for (int m = 1; m < 16; m <<= 1) {
#pragma unroll
        for (int j = 0; j < 16; ++j) {
            if (!(j & m)) {
                int k = j | m;
                float4 a = v[j], b = v[k];
                v[j] = make_float4(a.x + b.x, a.y + b.y, a.z + b.z, a.w + b.w);
                v[k] = make_float4(a.x - b.x, a.y - b.y, a.z - b.z, a.w - b.w);
            }
        }
    }
}

// One wave per row: out_row = s1 * FWHT( g * FWHT( s2 * x_row ) )
__global__ void __launch_bounds__(256, 2)
whvi_main(const float* __restrict__ x, const float* __restrict__ s1,
          const float* __restrict__ s2, const float* __restrict__ g,
          float* __restrict__ out) {
    const int lane = threadIdx.x & 63;
    const int row  = blockIdx.x * 4 + (threadIdx.x >> 6);
    if (row >= ROWS) return;

    const float4* __restrict__ xr  = (const float4*)(x + (size_t)row * DIM);
    float4* __restrict__       orw = (float4*)(out + (size_t)row * DIM);
    const float4* __restrict__ s2v = (const float4*)s2;
    const float4* __restrict__ gv  = (const float4*)g;
    const float4* __restrict__ s1v = (const float4*)s1;

    float sg[6];
#pragma unroll
    for (int s = 0; s < 6; ++s)
        sg[s] = (lane & (1 << s)) ? -1.0f : 1.0f;

    float4 v[16];
#pragma unroll
    for (int j = 0; j < 16; ++j)
        v[j] = f4mul(xr[lane + 64 * j], s2v[lane + 64 * j]);

    fwht4096(v, sg);

#pragma unroll
    for (int j = 0; j < 16; ++j)
        v[j] = f4mul(v[j], gv[lane + 64 * j]);

    fwht4096(v, sg);

#pragma unroll
    for (int j = 0; j < 16; ++j)
        orw[lane + 64 * j] = f4mul(v[j], s1v[lane + 64 * j]);
}

extern "C" void kernel_launch(void* const* d_in, const int* in_sizes, int n_in,
                              void* d_out, int out_size, void* d_ws, size_t ws_size,
                              hipStream_t stream) {
    // setup_inputs order: x, epsilon, s1, s2, g_mu, g_rho
    const float* x     = (const float*)d_in[0];
    const float* eps   = (const float*)d_in[1];
    const float* s1    = (const float*)d_in[2];
    const float* s2    = (const float*)d_in[3];
    const float* g_mu  = (const float*)d_in[4];
    const float* g_rho = (const float*)d_in[5];
    float* out = (float*)d_out;
    float* g   = (float*)d_ws;   // 4096 floats = 16 KB scratch

    g_precompute<<<DIM / 256, 256, 0, stream>>>(eps, g_mu, g_rho, g, DIM);
    // 2048 rows, 1 wave/row, 4 waves per 256-thread block
    whvi_main<<<ROWS / 4, 256, 0, stream>>>(x, s1, s2, g, out);
}

// Round 2
// 100.937 us; speedup vs baseline: 1.0597x; 1.0597x over previous
//
#include <hip/hip_runtime.h>
#include <math.h>

#define DIM 4096     // D: 12 FWHT stages
#define ROWS 2048    // B
#define LSTR 65      // LDS row stride (64 + 1 pad): conflict-free both phases

// ---- pre-kernel: g_t in TRANSPOSED layout for the mid-pipeline multiply.
// Layout B: lane l' (l' = 4*r' + i'), register m holds element
// e = 256*r' + 4*m + i'.  g_t[l'*64 + m] = g[e].
__global__ void g_precompute(const float* __restrict__ eps,
                             const float* __restrict__ g_mu,
                             const float* __restrict__ g_rho,
                             float* __restrict__ g_t) {
    int t = blockIdx.x * blockDim.x + threadIdx.x;   // 0..4095
    int lp = t >> 6, m = t & 63;
    int j = 256 * (lp >> 2) + 4 * m + (lp & 3);
    float sp = log1pf(expf(g_rho[j]));               // g_rho ~ [-5,-4], safe
    g_t[t] = g_mu[j] + sp * eps[j];
}

__device__ __forceinline__ float4 f4mul(float4 a, float4 b) {
    return make_float4(a.x * b.x, a.y * b.y, a.z * b.z, a.w * b.w);
}

// 6 in-register stages over layout A: bits i = e[0:2) (inside float4) and
// bits r = e[8:12) (across the 16 float4 regs).
__device__ __forceinline__ void fwht_ri(float4 v[16]) {
#pragma unroll
    for (int j = 0; j < 16; ++j) {
        float4 a = v[j];
        float t0 = a.x + a.y, t1 = a.x - a.y;
        float t2 = a.z + a.w, t3 = a.z - a.w;
        v[j] = make_float4(t0 + t2, t1 + t3, t0 - t2, t1 - t3);
    }
#pragma unroll
    for (int m = 1; m < 16; m <<= 1) {
#pragma unroll
        for (int j = 0; j < 16; ++j) {
            if (!(j & m)) {
                int k = j | m;
                float4 a = v[j], b = v[k];
                v[j] = make_float4(a.x + b.x, a.y + b.y, a.z + b.z, a.w + b.w);
                v[k] = make_float4(a.x - b.x, a.y - b.y, a.z - b.z, a.w - b.w);
            }
        }
    }
}

// 6 in-register stages over layout B: bits m = e[2:8) (the old lane bits).
__device__ __forceinline__ void fwht_m(float f[64]) {
#pragma unroll
    for (int s = 0; s < 6; ++s) {
        const int h = 1 << s;
#pragma unroll
        for (int m = 0; m < 64; ++m) {
            if (!(m & h)) {
                const int k = m | h;
                float a = f[m], b = f[k];
                f[m] = a + b;
                f[k] = a - b;
            }
        }
    }
}

// One wave per row: out = s1 * FWHT( g * FWHT( s2 * x_row ) )
// Layout A: lane l, reg r, comp i -> e = 256r + 4l + i  (coalesced b128 I/O)
// Layout B: lane l', reg m       -> e = 256(l'>>2) + 4m + (l'&3)
__global__ void __launch_bounds__(256)
whvi_main(const float* __restrict__ x, const float* __restrict__ s1,
          const float* __restrict__ s2, const float* __restrict__ g_t,
          float* __restrict__ out) {
    const int lane = threadIdx.x & 63;
    const int wid  = threadIdx.x >> 6;
    const int row  = blockIdx.x * 4 + wid;

    __shared__ float lds[4 * 64 * LSTR];
    float* __restrict__ L = lds + wid * 64 * LSTR;   // wave-private region

    const float4* __restrict__ xr  = (const float4*)(x + (size_t)row * DIM);
    float4* __restrict__       orw = (float4*)(out + (size_t)row * DIM);
    const float4* __restrict__ s2v = (const float4*)s2;
    const float4* __restrict__ s1v = (const float4*)s1;
    const float4* __restrict__ gtv = (const float4*)g_t;

    // ---- load + s2 scale (layout A)
    float4 v[16];
#pragma unroll
    for (int r = 0; r < 16; ++r)
        v[r] = f4mul(xr[64 * r + lane], s2v[64 * r + lane]);

    // ---- FWHT1: (i,r) stages in-register
    fwht_ri(v);

    // ---- transpose A -> B.  write L[lane*65 + (4r+i)], read L[m*65 + lane]
#pragma unroll
    for (int r = 0; r < 16; ++r) {
        L[lane * LSTR + 4 * r + 0] = v[r].x;
        L[lane * LSTR + 4 * r + 1] = v[r].y;
        L[lane * LSTR + 4 * r + 2] = v[r].z;
        L[lane * LSTR + 4 * r + 3] = v[r].w;
    }
    float f[64];
#pragma unroll
    for (int m = 0; m < 64; ++m)
        f[m] = L[m * LSTR + lane];

    // ---- FWHT1: m stages in-register (completes FWHT1)
    fwht_m(f);

    // ---- g multiply (g_t is pre-transposed: contiguous per lane)
#pragma unroll
    for (int k = 0; k < 16; ++k) {
        float4 gg = gtv[lane * 16 + k];
        f[4 * k + 0] *= gg.x;
        f[4 * k + 1] *= gg.y;
        f[4 * k + 2] *= gg.z;
        f[4 * k + 3] *= gg.w;
    }

    // ---- FWHT2: m stages in-register
    fwht_m(f);

    // ---- transpose B -> A.  write L[lane*65 + m], read L[(4r+i)*65 + lane]
#pragma unroll
    for (int m = 0; m < 64; ++m)
        L[lane * LSTR + m] = f[m];
#pragma unroll
    for (int r = 0; r < 16; ++r) {
        v[r].x = L[(4 * r + 0) * LSTR + lane];
        v[r].y = L[(4 * r + 1) * LSTR + lane];
        v[r].z = L[(4 * r + 2) * LSTR + lane];
        v[r].w = L[(4 * r + 3) * LSTR + lane];
    }

    // ---- FWHT2: (i,r) stages (completes FWHT2)
    fwht_ri(v);

    // ---- s1 scale + coalesced store (layout A)
#pragma unroll
    for (int r = 0; r < 16; ++r)
        orw[64 * r + lane] = f4mul(v[r], s1v[64 * r + lane]);
}

extern "C" void kernel_launch(void* const* d_in, const int* in_sizes, int n_in,
                              void* d_out, int out_size, void* d_ws, size_t ws_size,
                              hipStream_t stream) {
    // setup_inputs order: x, epsilon, s1, s2, g_mu, g_rho
    const float* x     = (const float*)d_in[0];
    const float* eps   = (const float*)d_in[1];
    const float* s1    = (const float*)d_in[2];
    const float* s2    = (const float*)d_in[3];
    const float* g_mu  = (const float*)d_in[4];
    const float* g_rho = (const float*)d_in[5];
    float* out = (float*)d_out;
    float* g_t = (float*)d_ws;   // 4096 floats = 16 KB scratch

    g_precompute<<<DIM / 256, 256, 0, stream>>>(eps, g_mu, g_rho, g_t);
    // 2048 rows, 1 wave/row, 4 waves per block; LDS 66.5 KB -> 2 blocks/CU
    whvi_main<<<ROWS / 4, 256, 0, stream>>>(x, s1, s2, g_t, out);
}